// Round 1
// baseline (1088.463 us; speedup 1.0000x reference)
//
#include <hip/hip_runtime.h>
#include <hip/hip_bf16.h>

// RCNN: bidirectional simple-RNN + conv1x1 + global max pool + dense sigmoid
// B=256 T=512 V=50000 E=128 H=256 C=128 K=2

#define B_ 256
#define T_ 512
#define E_ 128
#define H_ 256
#define C_ 128

typedef __attribute__((ext_vector_type(8))) short short8;
typedef __attribute__((ext_vector_type(4))) float float4v;

__device__ inline unsigned short f2bf(float f) {
  unsigned u = __float_as_uint(f);
  u += 0x7fffu + ((u >> 16) & 1u);   // round-to-nearest-even
  return (unsigned short)(u >> 16);
}
__device__ inline float bf2f(unsigned short h) {
  return __uint_as_float(((unsigned)h) << 16);
}
__device__ inline float fast_tanh(float x) {
  x = fminf(fmaxf(x, -15.f), 15.f);
  float e = __expf(2.f * x);
  return (e - 1.f) / (e + 1.f);
}
// monotonic float -> uint encoding for atomicMax-based fmax
__device__ inline unsigned enc_f(float f) {
  unsigned u = __float_as_uint(f);
  return (u & 0x80000000u) ? ~u : (u | 0x80000000u);
}
__device__ inline float dec_f(unsigned key) {
  unsigned bits = (key & 0x80000000u) ? (key ^ 0x80000000u) : ~key;
  return __uint_as_float(bits);
}

// ---------------------------------------------------------------------------
// prep: transpose + bf16-cast weights.  WfT/WbT:[256][128]  WcT:[128][640]
// UfT/UbT:[256][256]   (all [n][k] so MFMA B-fragments are contiguous in k)
// ---------------------------------------------------------------------------
__global__ __launch_bounds__(256) void prep_kernel(
    const float* __restrict__ Wf, const float* __restrict__ Wb,
    const float* __restrict__ Wc, const float* __restrict__ Uf,
    const float* __restrict__ Ub,
    unsigned short* __restrict__ WfT, unsigned short* __restrict__ WbT,
    unsigned short* __restrict__ WcT, unsigned short* __restrict__ UfT,
    unsigned short* __restrict__ UbT) {
  int gid = blockIdx.x * 256 + threadIdx.x;
  int stride = gridDim.x * 256;
  for (int i = gid; i < 256 * 128; i += stride) {
    int n = i >> 7, k = i & 127;
    WfT[i] = f2bf(Wf[k * 256 + n]);
    WbT[i] = f2bf(Wb[k * 256 + n]);
  }
  for (int i = gid; i < 128 * 640; i += stride) {
    int n = i / 640, k = i - n * 640;
    WcT[i] = f2bf(Wc[k * 128 + n]);
  }
  for (int i = gid; i < 256 * 256; i += stride) {
    int n = i >> 8, k = i & 255;
    UfT[i] = f2bf(Uf[k * 256 + n]);
    UbT[i] = f2bf(Ub[k * 256 + n]);
  }
}

// ---------------------------------------------------------------------------
// embxw: xw = emb[idx] @ W + b  -> bf16, written IN PLACE into concat buffer
// x[B*T][640]: dir0 -> cols [0,256)  dir1 -> cols [384,640)
// grid (2048, 2), 256 thr (4 waves); M-tile 64, N=256 (64 cols per wave)
// ---------------------------------------------------------------------------
__global__ __launch_bounds__(256) void embxw_kernel(
    const int* __restrict__ idxL, const int* __restrict__ idxR,
    const float* __restrict__ emb,
    const unsigned short* __restrict__ WfT, const unsigned short* __restrict__ WbT,
    const float* __restrict__ bf_, const float* __restrict__ bb_,
    unsigned short* __restrict__ x) {
  const int dir = blockIdx.y;
  const int* __restrict__ idx = dir ? idxR : idxL;
  const unsigned short* __restrict__ WT = dir ? WbT : WfT;
  const float* __restrict__ bias = dir ? bb_ : bf_;
  const int colout = dir ? 384 : 0;
  const int rowbase = blockIdx.x * 64;
  const int tid = threadIdx.x;
  const int wave = tid >> 6, lane = tid & 63;
  const int quad = lane >> 4, l15 = lane & 15;

  int eidx[4];
#pragma unroll
  for (int mt = 0; mt < 4; ++mt) eidx[mt] = idx[rowbase + mt * 16 + l15];

  float4v acc[4][4];
#pragma unroll
  for (int mt = 0; mt < 4; ++mt)
#pragma unroll
    for (int ct = 0; ct < 4; ++ct) acc[mt][ct] = (float4v){0.f, 0.f, 0.f, 0.f};

#pragma unroll
  for (int kt = 0; kt < 4; ++kt) {
    const int k0 = kt * 32 + quad * 8;
    short8 afr[4];
#pragma unroll
    for (int mt = 0; mt < 4; ++mt) {
      const float* ap = emb + (size_t)eidx[mt] * E_ + k0;
      float4v a0 = *(const float4v*)ap;
      float4v a1 = *(const float4v*)(ap + 4);
      short8 f;
      f[0] = (short)f2bf(a0[0]); f[1] = (short)f2bf(a0[1]);
      f[2] = (short)f2bf(a0[2]); f[3] = (short)f2bf(a0[3]);
      f[4] = (short)f2bf(a1[0]); f[5] = (short)f2bf(a1[1]);
      f[6] = (short)f2bf(a1[2]); f[7] = (short)f2bf(a1[3]);
      afr[mt] = f;
    }
    short8 bfr[4];
#pragma unroll
    for (int ct = 0; ct < 4; ++ct) {
      int n = wave * 64 + ct * 16 + l15;
      bfr[ct] = *(const short8*)(WT + n * 128 + k0);
    }
#pragma unroll
    for (int mt = 0; mt < 4; ++mt)
#pragma unroll
      for (int ct = 0; ct < 4; ++ct)
        acc[mt][ct] = __builtin_amdgcn_mfma_f32_16x16x32_bf16(
            afr[mt], bfr[ct], acc[mt][ct], 0, 0, 0);
  }
#pragma unroll
  for (int ct = 0; ct < 4; ++ct) {
    int n = wave * 64 + ct * 16 + l15;
    float bv = bias[n];
#pragma unroll
    for (int mt = 0; mt < 4; ++mt)
#pragma unroll
      for (int i = 0; i < 4; ++i) {
        int r = rowbase + mt * 16 + quad * 4 + i;
        x[(size_t)r * 640 + colout + n] = f2bf(acc[mt][ct][i] + bv);
      }
  }
}

// ---------------------------------------------------------------------------
// ecur: e_cur = emb[input_current] -> bf16 into x cols [256,384)
// ---------------------------------------------------------------------------
__global__ __launch_bounds__(256) void ecur_kernel(
    const int* __restrict__ idxC, const float* __restrict__ emb,
    unsigned short* __restrict__ x) {
  int tid = blockIdx.x * 256 + threadIdx.x;  // 2,097,152 total
  int r = tid >> 4;
  int c = (tid & 15) * 8;
  int e = idxC[r];
  const float* p = emb + (size_t)e * E_ + c;
  float4v a0 = *(const float4v*)p;
  float4v a1 = *(const float4v*)(p + 4);
  short8 f;
  f[0] = (short)f2bf(a0[0]); f[1] = (short)f2bf(a0[1]);
  f[2] = (short)f2bf(a0[2]); f[3] = (short)f2bf(a0[3]);
  f[4] = (short)f2bf(a1[0]); f[5] = (short)f2bf(a1[1]);
  f[6] = (short)f2bf(a1[2]); f[7] = (short)f2bf(a1[3]);
  *(short8*)(x + (size_t)r * 640 + 256 + c) = f;
}

// ---------------------------------------------------------------------------
// rnn: h_t = tanh(xw_t + h_{t-1} @ U), in-place over xw in x buffer.
// 32 blocks (16 batch-tiles x 2 dirs), 512 thr (8 waves, 32 cols each).
// U fragments live in registers (loaded once); h double-buffered in LDS.
// xw prefetched 1 step ahead; h global-store deferred 1 step (hide vmcnt).
// ---------------------------------------------------------------------------
__global__ __launch_bounds__(512) void rnn_kernel(
    unsigned short* __restrict__ x,
    const unsigned short* __restrict__ UfT,
    const unsigned short* __restrict__ UbT) {
  const int dir = blockIdx.x & 1;
  const int b0 = (blockIdx.x >> 1) * 16;
  const unsigned short* __restrict__ UT = dir ? UbT : UfT;
  const int colout = dir ? 384 : 0;
  const int tid = threadIdx.x;
  const int wave = tid >> 6, lane = tid & 63;
  const int quad = lane >> 4, l15 = lane & 15;
  const int colbase = wave * 32;

  __shared__ __attribute__((aligned(16))) unsigned short hbuf[2][16][264];

  for (int i = tid; i < 16 * 264; i += 512) ((unsigned short*)hbuf[0])[i] = 0;

  // U B-fragments in registers: 2 col-tiles x 8 k-tiles x 4 VGPRs
  short8 ufr[2][8];
#pragma unroll
  for (int ct = 0; ct < 2; ++ct)
#pragma unroll
    for (int kt = 0; kt < 8; ++kt) {
      int n = colbase + ct * 16 + l15;
      ufr[ct][kt] = *(const short8*)(UT + n * 256 + kt * 32 + quad * 8);
    }

  // per-lane xw/h pointers (element (ct,i): batch row quad*4+i, col n)
  unsigned short* xp[2][4];
#pragma unroll
  for (int ct = 0; ct < 2; ++ct)
#pragma unroll
    for (int i = 0; i < 4; ++i)
      xp[ct][i] = x + (size_t)(b0 + quad * 4 + i) * T_ * 640 + colout +
                  colbase + ct * 16 + l15;

  __syncthreads();

  const int tstep = dir ? -1 : 1;
  int tt = dir ? (T_ - 1) : 0;

  unsigned short cur[2][4];
#pragma unroll
  for (int ct = 0; ct < 2; ++ct)
#pragma unroll
    for (int i = 0; i < 4; ++i) cur[ct][i] = xp[ct][i][tt * 640];

  unsigned short hst[2][4];
  int ttprev = tt;

#pragma unroll 1
  for (int s = 0; s < T_; ++s) {
    // deferred global store of previous step's h (drains during this step)
    if (s > 0) {
#pragma unroll
      for (int ct = 0; ct < 2; ++ct)
#pragma unroll
        for (int i = 0; i < 4; ++i) xp[ct][i][ttprev * 640] = hst[ct][i];
    }
    // prefetch next step's xw
    unsigned short nxt[2][4];
    if (s < T_ - 1) {
      int ttn = tt + tstep;
#pragma unroll
      for (int ct = 0; ct < 2; ++ct)
#pragma unroll
        for (int i = 0; i < 4; ++i) nxt[ct][i] = xp[ct][i][ttn * 640];
    }
    // A fragments from LDS (identical across waves; 2-way bank alias = free)
    short8 afr[8];
#pragma unroll
    for (int kt = 0; kt < 8; ++kt)
      afr[kt] = *(const short8*)&hbuf[s & 1][l15][kt * 32 + quad * 8];

    float4v acc[2];
    acc[0] = (float4v){0.f, 0.f, 0.f, 0.f};
    acc[1] = (float4v){0.f, 0.f, 0.f, 0.f};
#pragma unroll
    for (int kt = 0; kt < 8; ++kt) {
      acc[0] = __builtin_amdgcn_mfma_f32_16x16x32_bf16(afr[kt], ufr[0][kt],
                                                       acc[0], 0, 0, 0);
      acc[1] = __builtin_amdgcn_mfma_f32_16x16x32_bf16(afr[kt], ufr[1][kt],
                                                       acc[1], 0, 0, 0);
    }
#pragma unroll
    for (int ct = 0; ct < 2; ++ct)
#pragma unroll
      for (int i = 0; i < 4; ++i) {
        float pre = acc[ct][i] + bf2f(cur[ct][i]);
        unsigned short hb = f2bf(fast_tanh(pre));
        hbuf[(s + 1) & 1][quad * 4 + i][colbase + ct * 16 + l15] = hb;
        hst[ct][i] = hb;
      }
#pragma unroll
    for (int ct = 0; ct < 2; ++ct)
#pragma unroll
      for (int i = 0; i < 4; ++i) cur[ct][i] = nxt[ct][i];
    ttprev = tt;
    tt += tstep;
    __syncthreads();
  }
  // final step's h
#pragma unroll
  for (int ct = 0; ct < 2; ++ct)
#pragma unroll
    for (int i = 0; i < 4; ++i) xp[ct][i][ttprev * 640] = hst[ct][i];
}

// ---------------------------------------------------------------------------
// convpool: tanh(x @ Wc + bc), max over rows of its 64-row tile, atomicMax.
// grid 2048 (M-tile 64, one batch each), 256 thr (4 waves, 32 cols each)
// ---------------------------------------------------------------------------
__global__ __launch_bounds__(256) void convpool_kernel(
    const unsigned short* __restrict__ x, const unsigned short* __restrict__ WcT,
    const float* __restrict__ bc, unsigned int* __restrict__ pooled) {
  const int rowbase = blockIdx.x * 64;
  const int b = rowbase >> 9;  // /512
  const int tid = threadIdx.x;
  const int wave = tid >> 6, lane = tid & 63;
  const int quad = lane >> 4, l15 = lane & 15;

  float4v acc[4][2];
#pragma unroll
  for (int mt = 0; mt < 4; ++mt)
#pragma unroll
    for (int ct = 0; ct < 2; ++ct) acc[mt][ct] = (float4v){0.f, 0.f, 0.f, 0.f};

#pragma unroll 2
  for (int kt = 0; kt < 20; ++kt) {
    const int k0 = kt * 32 + quad * 8;
    short8 bfr[2];
#pragma unroll
    for (int ct = 0; ct < 2; ++ct) {
      int n = wave * 32 + ct * 16 + l15;
      bfr[ct] = *(const short8*)(WcT + n * 640 + k0);
    }
#pragma unroll
    for (int mt = 0; mt < 4; ++mt) {
      short8 afr = *(const short8*)(x + (size_t)(rowbase + mt * 16 + l15) * 640 + k0);
      acc[mt][0] = __builtin_amdgcn_mfma_f32_16x16x32_bf16(afr, bfr[0],
                                                           acc[mt][0], 0, 0, 0);
      acc[mt][1] = __builtin_amdgcn_mfma_f32_16x16x32_bf16(afr, bfr[1],
                                                           acc[mt][1], 0, 0, 0);
    }
  }
#pragma unroll
  for (int ct = 0; ct < 2; ++ct) {
    int n = wave * 32 + ct * 16 + l15;
    float bv = bc[n];
    float mx = -1e30f;
#pragma unroll
    for (int mt = 0; mt < 4; ++mt)
#pragma unroll
      for (int i = 0; i < 4; ++i)
        mx = fmaxf(mx, fast_tanh(acc[mt][ct][i] + bv));
    mx = fmaxf(mx, __shfl_xor(mx, 16, 64));
    mx = fmaxf(mx, __shfl_xor(mx, 32, 64));
    if (quad == 0) atomicMax(pooled + b * C_ + n, enc_f(mx));
  }
}

// ---------------------------------------------------------------------------
// dense: out = sigmoid(pooled @ Wd + bd)   [256,128]@[128,2]
// ---------------------------------------------------------------------------
__global__ __launch_bounds__(256) void dense_kernel(
    const unsigned int* __restrict__ pooled, const float* __restrict__ Wd,
    const float* __restrict__ bd, float* __restrict__ out) {
  int b = threadIdx.x;  // one block of 256
  float s0 = bd[0], s1 = bd[1];
#pragma unroll 4
  for (int c = 0; c < C_; ++c) {
    float f = dec_f(pooled[b * C_ + c]);
    s0 += f * Wd[c * 2 + 0];
    s1 += f * Wd[c * 2 + 1];
  }
  out[b * 2 + 0] = 1.f / (1.f + __expf(-s0));
  out[b * 2 + 1] = 1.f / (1.f + __expf(-s1));
}

// ---------------------------------------------------------------------------
extern "C" void kernel_launch(void* const* d_in, const int* in_sizes, int n_in,
                              void* d_out, int out_size, void* d_ws, size_t ws_size,
                              hipStream_t stream) {
  const int* idxC = (const int*)d_in[0];
  const int* idxL = (const int*)d_in[1];
  const int* idxR = (const int*)d_in[2];
  const float* emb = (const float*)d_in[3];
  const float* Wf = (const float*)d_in[4];
  const float* Uf = (const float*)d_in[5];
  const float* bf_ = (const float*)d_in[6];
  const float* Wb = (const float*)d_in[7];
  const float* Ub = (const float*)d_in[8];
  const float* bb_ = (const float*)d_in[9];
  const float* Wc = (const float*)d_in[10];
  const float* bc = (const float*)d_in[11];
  const float* Wd = (const float*)d_in[12];
  const float* bd = (const float*)d_in[13];

  char* ws = (char*)d_ws;
  // x concat buffer [B*T][640] bf16 = 167,772,160 B
  unsigned short* x = (unsigned short*)ws;
  unsigned int* pooled = (unsigned int*)(ws + 167772160);          // 131072 B
  unsigned short* WfT = (unsigned short*)(ws + 167772160 + 131072); // 65536 B
  unsigned short* WbT = WfT + 256 * 128;                            // 65536 B
  unsigned short* WcT = WbT + 256 * 128;                            // 163840 B
  unsigned short* UfT = WcT + 128 * 640;                            // 131072 B
  unsigned short* UbT = UfT + 256 * 256;                            // 131072 B

  hipMemsetAsync(pooled, 0, B_ * C_ * sizeof(unsigned int), stream);
  prep_kernel<<<64, 256, 0, stream>>>(Wf, Wb, Wc, Uf, Ub, WfT, WbT, WcT, UfT, UbT);
  embxw_kernel<<<dim3(2048, 2), 256, 0, stream>>>(idxL, idxR, emb, WfT, WbT, bf_, bb_, x);
  ecur_kernel<<<8192, 256, 0, stream>>>(idxC, emb, x);
  rnn_kernel<<<32, 512, 0, stream>>>(x, UfT, UbT);
  convpool_kernel<<<2048, 256, 0, stream>>>(x, WcT, bc, pooled);
  dense_kernel<<<1, 256, 0, stream>>>(pooled, Wd, bd, (float*)d_out);
}

// Round 2
// 1030.552 us; speedup vs baseline: 1.0562x; 1.0562x over previous
//
#include <hip/hip_runtime.h>
#include <hip/hip_bf16.h>

// RCNN: bidirectional simple-RNN + conv1x1 (fused) + global max pool + dense
// B=256 T=512 V=50000 E=128 H=256 C=128
//
// Key layout: "unit" = 512 B = 64 lanes x 8 B (4 bf16). For a 16-batch tile
// b0 at time t, unit u (u=0..15 for xw, 0..7 for p) lives in x-row
// (b0+u)*T + t. Lane (q=lane>>4, l15=lane&15) of a unit holds columns
// 16u+4q+0..3 of batch b0+l15. All GEMMs are computed transposed
// (D[m=out-col][n=batch]) so the MFMA C-layout emits 4 consecutive columns
// per lane -> b64 LDS writes and packed b64 global stores.
//
// rnn writes p = h @ Wc_slice (conv partial) instead of h, time-shifted by
// D=4 slots into the consumed xw region, allowing a barrier WITHOUT vmcnt
// drain (>=5 barriers separate any xw load from the p store over it).

#define B_ 256
#define T_ 512
#define E_ 128
#define H_ 256
#define C_ 128

typedef __attribute__((ext_vector_type(8))) short short8;
typedef __attribute__((ext_vector_type(4))) float float4v;
typedef __attribute__((ext_vector_type(2))) unsigned int uint2v;

__device__ inline unsigned short f2bf(float f) {
  unsigned u = __float_as_uint(f);
  u += 0x7fffu + ((u >> 16) & 1u);  // RNE
  return (unsigned short)(u >> 16);
}
__device__ inline unsigned pkbf(float a, float b) {
  __hip_bfloat162 h2 = __float22bfloat162_rn(float2{a, b});
  union { __hip_bfloat162 h; unsigned u; } cv;
  cv.h = h2;
  return cv.u;
}
__device__ inline float lo16f(unsigned u) { return __uint_as_float(u << 16); }
__device__ inline float hi16f(unsigned u) { return __uint_as_float(u & 0xffff0000u); }
__device__ inline float fast_tanh(float x) {
  float e = __expf(2.f * x);                 // inf ok: -> 1
  float r = __builtin_amdgcn_rcpf(e + 1.f);  // ~1ulp
  return __builtin_fmaf(-2.f, r, 1.f);
}
__device__ inline unsigned enc_f(float f) {
  unsigned u = __float_as_uint(f);
  return (u & 0x80000000u) ? ~u : (u | 0x80000000u);
}
__device__ inline float dec_f(unsigned key) {
  unsigned bits = (key & 0x80000000u) ? (key ^ 0x80000000u) : ~key;
  return __uint_as_float(bits);
}
// barrier that drains LDS only (global loads/stores stay in flight)
__device__ inline void sync_lds() {
  asm volatile("s_waitcnt lgkmcnt(0)\n\ts_barrier" ::: "memory");
}

// ---------------------------------------------------------------------------
// prep: transpose + bf16-cast weights. WfT/WbT:[256][128] WcT:[128][640]
// UfT/UbT:[256][256]  (all [n][k])
// ---------------------------------------------------------------------------
__global__ __launch_bounds__(256) void prep_kernel(
    const float* __restrict__ Wf, const float* __restrict__ Wb,
    const float* __restrict__ Wc, const float* __restrict__ Uf,
    const float* __restrict__ Ub,
    unsigned short* __restrict__ WfT, unsigned short* __restrict__ WbT,
    unsigned short* __restrict__ WcT, unsigned short* __restrict__ UfT,
    unsigned short* __restrict__ UbT) {
  int gid = blockIdx.x * 256 + threadIdx.x;
  int stride = gridDim.x * 256;
  for (int i = gid; i < 256 * 128; i += stride) {
    int n = i >> 7, k = i & 127;
    WfT[i] = f2bf(Wf[k * 256 + n]);
    WbT[i] = f2bf(Wb[k * 256 + n]);
  }
  for (int i = gid; i < 128 * 640; i += stride) {
    int n = i / 640, k = i - n * 640;
    WcT[i] = f2bf(Wc[k * 128 + n]);
  }
  for (int i = gid; i < 256 * 256; i += stride) {
    int n = i >> 8, k = i & 255;
    UfT[i] = f2bf(Uf[k * 256 + n]);
    UbT[i] = f2bf(Ub[k * 256 + n]);
  }
}

// ---------------------------------------------------------------------------
// embxw: xw^T = W^T . e^T + b, written as packed units into x.
// grid (128 tquads, 16 btiles, 2 dirs), 256 thr (4 waves, 64 out-cols each).
// ---------------------------------------------------------------------------
__global__ __launch_bounds__(256) void embxw_kernel(
    const int* __restrict__ idxL, const int* __restrict__ idxR,
    const float* __restrict__ emb,
    const unsigned short* __restrict__ WfT, const unsigned short* __restrict__ WbT,
    const float* __restrict__ bfv, const float* __restrict__ bbv,
    unsigned short* __restrict__ x) {
  const int dir = blockIdx.z;
  const int* __restrict__ idx = dir ? idxR : idxL;
  const unsigned short* __restrict__ WT = dir ? WbT : WfT;
  const float* __restrict__ bias = dir ? bbv : bfv;
  const int t0 = blockIdx.x * 4;
  const int b0 = blockIdx.y * 16;
  const int tid = threadIdx.x;
  const int w = tid >> 6, lane = tid & 63, q = lane >> 4, l15 = lane & 15;

  // A-fragments of W^T: A[m=64w+16mt+l15][k=kt*32+q*8]
  short8 wfr[4][4];
#pragma unroll
  for (int mt = 0; mt < 4; ++mt)
#pragma unroll
    for (int kt = 0; kt < 4; ++kt)
      wfr[mt][kt] = *(const short8*)(WT + (64 * w + 16 * mt + l15) * 128 +
                                     kt * 32 + q * 8);
  float4v bv[4];
#pragma unroll
  for (int mt = 0; mt < 4; ++mt)
    bv[mt] = *(const float4v*)(bias + 64 * w + 16 * mt + 4 * q);

#pragma unroll 1
  for (int j = 0; j < 4; ++j) {
    const int t = t0 + j;
    const int er = idx[(b0 + l15) * T_ + t];
    const float* ep = emb + (size_t)er * E_;
    short8 efr[4];
#pragma unroll
    for (int kt = 0; kt < 4; ++kt) {
      const float* p8 = ep + kt * 32 + q * 8;
      float4v a0 = *(const float4v*)p8;
      float4v a1 = *(const float4v*)(p8 + 4);
      union { unsigned u[4]; short8 s; } cv;
      cv.u[0] = pkbf(a0[0], a0[1]);
      cv.u[1] = pkbf(a0[2], a0[3]);
      cv.u[2] = pkbf(a1[0], a1[1]);
      cv.u[3] = pkbf(a1[2], a1[3]);
      efr[kt] = cv.s;
    }
    float4v acc[4];
#pragma unroll
    for (int mt = 0; mt < 4; ++mt) acc[mt] = (float4v){0.f, 0.f, 0.f, 0.f};
#pragma unroll
    for (int kt = 0; kt < 4; ++kt)
#pragma unroll
      for (int mt = 0; mt < 4; ++mt)
        acc[mt] = __builtin_amdgcn_mfma_f32_16x16x32_bf16(wfr[mt][kt], efr[kt],
                                                          acc[mt], 0, 0, 0);
#pragma unroll
    for (int mt = 0; mt < 4; ++mt) {
      float4v v = acc[mt] + bv[mt];
      uint2v pk = {pkbf(v[0], v[1]), pkbf(v[2], v[3])};
      *(uint2v*)(x + ((size_t)(b0 + 4 * w + mt) * T_ + t) * 640 + dir * 384 +
                 lane * 4) = pk;
    }
  }
}

// ---------------------------------------------------------------------------
// pcur: p_c^T = Wc[256:384]^T . e_cur^T + bc, packed units (split-lane rows)
// into x bytes [512,768) of each row. grid (128,16), 256 thr.
// ---------------------------------------------------------------------------
__global__ __launch_bounds__(256) void pcur_kernel(
    const int* __restrict__ idxC, const float* __restrict__ emb,
    const unsigned short* __restrict__ WcT, const float* __restrict__ bc,
    unsigned short* __restrict__ x) {
  const int t0 = blockIdx.x * 4;
  const int b0 = blockIdx.y * 16;
  const int tid = threadIdx.x;
  const int w = tid >> 6, lane = tid & 63, q = lane >> 4, l15 = lane & 15;

  short8 wfr[2][4];
#pragma unroll
  for (int mt = 0; mt < 2; ++mt)
#pragma unroll
    for (int kt = 0; kt < 4; ++kt)
      wfr[mt][kt] = *(const short8*)(WcT +
                                     (size_t)(16 * (2 * w + mt) + l15) * 640 +
                                     256 + kt * 32 + q * 8);
  float4v bv[2];
#pragma unroll
  for (int mt = 0; mt < 2; ++mt)
    bv[mt] = *(const float4v*)(bc + 16 * (2 * w + mt) + 4 * q);

#pragma unroll 1
  for (int j = 0; j < 4; ++j) {
    const int t = t0 + j;
    const int er = idxC[(b0 + l15) * T_ + t];
    const float* ep = emb + (size_t)er * E_;
    short8 efr[4];
#pragma unroll
    for (int kt = 0; kt < 4; ++kt) {
      const float* p8 = ep + kt * 32 + q * 8;
      float4v a0 = *(const float4v*)p8;
      float4v a1 = *(const float4v*)(p8 + 4);
      union { unsigned u[4]; short8 s; } cv;
      cv.u[0] = pkbf(a0[0], a0[1]);
      cv.u[1] = pkbf(a0[2], a0[3]);
      cv.u[2] = pkbf(a1[0], a1[1]);
      cv.u[3] = pkbf(a1[2], a1[3]);
      efr[kt] = cv.s;
    }
    float4v acc[2];
    acc[0] = (float4v){0.f, 0.f, 0.f, 0.f};
    acc[1] = (float4v){0.f, 0.f, 0.f, 0.f};
#pragma unroll
    for (int kt = 0; kt < 4; ++kt)
#pragma unroll
      for (int mt = 0; mt < 2; ++mt)
        acc[mt] = __builtin_amdgcn_mfma_f32_16x16x32_bf16(wfr[mt][kt], efr[kt],
                                                          acc[mt], 0, 0, 0);
#pragma unroll
    for (int mt = 0; mt < 2; ++mt) {
      float4v v = acc[mt] + bv[mt];
      uint2v pk = {pkbf(v[0], v[1]), pkbf(v[2], v[3])};
      int row = b0 + 2 * w + mt + ((q >= 2) ? 8 : 0);
      *(uint2v*)(x + ((size_t)row * T_ + t) * 640 + 256 + (lane & 31) * 4) = pk;
    }
  }
}

// ---------------------------------------------------------------------------
// rnn: h_t = tanh(xw_t + U^T h^T), fused p = Wc_slice^T h^T written (shifted
// by D=4 slots) over consumed xw. 32 blocks (16 btiles x 2 dirs), 256 thr
// (4 waves x 64 h-cols + 32 p-cols). U/Wc fragments in registers; h in LDS.
// Barrier drains LDS only — global ops pipeline across steps.
// ---------------------------------------------------------------------------
__global__ __launch_bounds__(256, 1) void rnn_kernel(
    unsigned short* x, const unsigned short* __restrict__ UfT,
    const unsigned short* __restrict__ UbT,
    const unsigned short* __restrict__ WcT) {
  const int dir = blockIdx.x & 1;
  const int b0 = (blockIdx.x >> 1) * 16;
  const unsigned short* __restrict__ UT = dir ? UbT : UfT;
  const int wcoff = dir ? 384 : 0;  // k-offset into WcT's 640
  const int xoff = dir ? 384 : 0;   // col offset (u16) in x row
  const int tstep = dir ? -1 : 1;
  const int t0 = dir ? (T_ - 1) : 0;
  const int dstep = tstep * 640;
  const int tid = threadIdx.x;
  const int w = tid >> 6, lane = tid & 63, q = lane >> 4, l15 = lane & 15;

  __shared__ __attribute__((aligned(16))) unsigned short hbuf[2][16][264];
  __shared__ unsigned pstash[4][8][64][2];
  unsigned short* hb = &hbuf[0][0][0];

  for (int i = tid; i < 16 * 264; i += 256) hb[i] = 0;

  // U^T A-fragments: [mt=4][kt=8]
  short8 ufr[4][8];
#pragma unroll
  for (int mt = 0; mt < 4; ++mt)
#pragma unroll
    for (int kt = 0; kt < 8; ++kt)
      ufr[mt][kt] = *(const short8*)(UT + (64 * w + 16 * mt + l15) * H_ +
                                     kt * 32 + q * 8);
  // Wc_slice^T A-fragments: [mt2=2][kt=8]
  short8 wcfr[2][8];
#pragma unroll
  for (int mt = 0; mt < 2; ++mt)
#pragma unroll
    for (int kt = 0; kt < 8; ++kt)
      wcfr[mt][kt] = *(const short8*)(WcT +
                                      (size_t)(16 * (2 * w + mt) + l15) * 640 +
                                      wcoff + kt * 32 + q * 8);

  // running xw unit pointers (next-step prefetch) + current values
  const unsigned short* xq[4];
  uint2v cur[4], nxt[4];
#pragma unroll
  for (int mt = 0; mt < 4; ++mt) {
    const unsigned short* base =
        x + (size_t)(b0 + 4 * w + mt) * T_ * 640 + xoff + lane * 4;
    cur[mt] = *(const uint2v*)(base + (size_t)t0 * 640);
    xq[mt] = base + (size_t)(t0 + tstep) * 640;
  }
  // running p store pointers (first store at slot t0)
  unsigned short* psl[2];
#pragma unroll
  for (int mt = 0; mt < 2; ++mt)
    psl[mt] = x + (size_t)(b0 + 2 * w + mt) * T_ * 640 + xoff + lane * 4 +
              (size_t)t0 * 640;

  __syncthreads();

  unsigned hrd = 0;  // LDS read offset (shorts); write = hrd ^ 4224

#pragma unroll 1
  for (int s = 0; s < T_; ++s) {
    // B-fragments of h(s-1)
    short8 afr[8];
#pragma unroll
    for (int kt = 0; kt < 8; ++kt)
      afr[kt] = *(const short8*)(hb + hrd + l15 * 264 + kt * 32 + q * 8);
    // prefetch next xw
    if (s < T_ - 1) {
#pragma unroll
      for (int mt = 0; mt < 4; ++mt) {
        nxt[mt] = *(const uint2v*)xq[mt];
        xq[mt] += dstep;
      }
    }
    // p-GEMM for previous step's h (independent latency filler)
    if (s >= 1) {
      float4v pacc[2];
      pacc[0] = (float4v){0.f, 0.f, 0.f, 0.f};
      pacc[1] = (float4v){0.f, 0.f, 0.f, 0.f};
#pragma unroll
      for (int kt = 0; kt < 8; ++kt)
#pragma unroll
        for (int mt = 0; mt < 2; ++mt)
          pacc[mt] = __builtin_amdgcn_mfma_f32_16x16x32_bf16(
              wcfr[mt][kt], afr[kt], pacc[mt], 0, 0, 0);
      if (s >= 5) {
#pragma unroll
        for (int mt = 0; mt < 2; ++mt) {
          uint2v pk = {pkbf(pacc[mt][0], pacc[mt][1]),
                       pkbf(pacc[mt][2], pacc[mt][3])};
          *(uint2v*)psl[mt] = pk;
          psl[mt] += dstep;
        }
      } else {
#pragma unroll
        for (int mt = 0; mt < 2; ++mt) {
          uint2v pk = {pkbf(pacc[mt][0], pacc[mt][1]),
                       pkbf(pacc[mt][2], pacc[mt][3])};
          *(uint2v*)&pstash[s - 1][2 * w + mt][lane][0] = pk;
        }
      }
    }
    // h-GEMM: D[m=out-col][n=batch]
    float4v acc[4];
#pragma unroll
    for (int mt = 0; mt < 4; ++mt) acc[mt] = (float4v){0.f, 0.f, 0.f, 0.f};
#pragma unroll
    for (int kt = 0; kt < 8; ++kt)
#pragma unroll
      for (int mt = 0; mt < 4; ++mt)
        acc[mt] = __builtin_amdgcn_mfma_f32_16x16x32_bf16(ufr[mt][kt], afr[kt],
                                                          acc[mt], 0, 0, 0);
    // epilogue: h = tanh(acc + xw); lane writes 4 consecutive cols -> b64
#pragma unroll
    for (int mt = 0; mt < 4; ++mt) {
      float p0 = acc[mt][0] + lo16f(cur[mt].x);
      float p1 = acc[mt][1] + hi16f(cur[mt].x);
      float p2 = acc[mt][2] + lo16f(cur[mt].y);
      float p3 = acc[mt][3] + hi16f(cur[mt].y);
      uint2v hv = {pkbf(fast_tanh(p0), fast_tanh(p1)),
                   pkbf(fast_tanh(p2), fast_tanh(p3))};
      *(uint2v*)(hb + (hrd ^ 4224) + l15 * 264 + 64 * w + 16 * mt + 4 * q) = hv;
    }
#pragma unroll
    for (int mt = 0; mt < 4; ++mt) cur[mt] = nxt[mt];
    hrd ^= 4224;
    sync_lds();
  }

  // post-loop: p for the last h (content t0+511*tstep) -> slot t0+507*tstep
  {
    short8 afr[8];
#pragma unroll
    for (int kt = 0; kt < 8; ++kt)
      afr[kt] = *(const short8*)(hb + hrd + l15 * 264 + kt * 32 + q * 8);
    float4v pacc[2];
    pacc[0] = (float4v){0.f, 0.f, 0.f, 0.f};
    pacc[1] = (float4v){0.f, 0.f, 0.f, 0.f};
#pragma unroll
    for (int kt = 0; kt < 8; ++kt)
#pragma unroll
      for (int mt = 0; mt < 2; ++mt)
        pacc[mt] = __builtin_amdgcn_mfma_f32_16x16x32_bf16(
            wcfr[mt][kt], afr[kt], pacc[mt], 0, 0, 0);
#pragma unroll
    for (int mt = 0; mt < 2; ++mt) {
      uint2v pk = {pkbf(pacc[mt][0], pacc[mt][1]),
                   pkbf(pacc[mt][2], pacc[mt][3])};
      *(uint2v*)psl[mt] = pk;  // psl now points at slot t0+507*tstep
    }
    // drain stash: contents t0+k*tstep (k=0..3) -> slots t0+(508+k)*tstep
#pragma unroll
    for (int k = 0; k < 4; ++k) {
      int slot = t0 + (508 + k) * tstep;
#pragma unroll
      for (int mt = 0; mt < 2; ++mt) {
        uint2v pk = *(uint2v*)&pstash[k][2 * w + mt][lane][0];
        *(uint2v*)(x + (size_t)(b0 + 2 * w + mt) * T_ * 640 + xoff + lane * 4 +
                   (size_t)slot * 640) = pk;
      }
    }
  }
}

// ---------------------------------------------------------------------------
// pool: out-max over t of tanh(p_f + p_c + p_b). grid 256 (16 btiles x 16
// tchunks of 32 t), 256 thr; wave handles 8 t. atomicMax(enc) into pooled.
// ---------------------------------------------------------------------------
__global__ __launch_bounds__(256) void pool_kernel(
    const unsigned short* __restrict__ x, unsigned int* __restrict__ pooled) {
  const int b0 = (blockIdx.x & 15) * 16;
  const int tc = blockIdx.x >> 4;
  const int tid = threadIdx.x;
  const int w = tid >> 6, lane = tid & 63, q = lane >> 4, l15 = lane & 15;

  float mx[8][4];
#pragma unroll
  for (int u = 0; u < 8; ++u)
#pragma unroll
    for (int i = 0; i < 4; ++i) mx[u][i] = -1e30f;

#pragma unroll 1
  for (int j = 0; j < 8; ++j) {
    const int t = tc * 32 + w * 8 + j;
    const int sf = (t >= 4) ? (t - 4) : (508 + t);
    const int sb = (t <= 507) ? (t + 4) : (t - 508);
#pragma unroll
    for (int u = 0; u < 8; ++u) {
      uint2v pf = *(const uint2v*)(x + ((size_t)(b0 + u) * T_ + sf) * 640 +
                                   lane * 4);
      uint2v pb = *(const uint2v*)(x + ((size_t)(b0 + u) * T_ + sb) * 640 +
                                   384 + lane * 4);
      int rc = b0 + u + ((q >= 2) ? 8 : 0);
      uint2v pc = *(const uint2v*)(x + ((size_t)rc * T_ + t) * 640 + 256 +
                                   (lane & 31) * 4);
      float v0 = lo16f(pf.x) + lo16f(pb.x) + lo16f(pc.x);
      float v1 = hi16f(pf.x) + hi16f(pb.x) + hi16f(pc.x);
      float v2 = lo16f(pf.y) + lo16f(pb.y) + lo16f(pc.y);
      float v3 = hi16f(pf.y) + hi16f(pb.y) + hi16f(pc.y);
      mx[u][0] = fmaxf(mx[u][0], fast_tanh(v0));
      mx[u][1] = fmaxf(mx[u][1], fast_tanh(v1));
      mx[u][2] = fmaxf(mx[u][2], fast_tanh(v2));
      mx[u][3] = fmaxf(mx[u][3], fast_tanh(v3));
    }
  }
#pragma unroll
  for (int u = 0; u < 8; ++u)
#pragma unroll
    for (int i = 0; i < 4; ++i)
      atomicMax(pooled + (b0 + l15) * C_ + 16 * u + 4 * q + i,
                enc_f(mx[u][i]));
}

// ---------------------------------------------------------------------------
// dense: out = sigmoid(pooled @ Wd + bd)  [256,128]@[128,2]
// ---------------------------------------------------------------------------
__global__ __launch_bounds__(256) void dense_kernel(
    const unsigned int* __restrict__ pooled, const float* __restrict__ Wd,
    const float* __restrict__ bd, float* __restrict__ out) {
  int b = threadIdx.x;
  float s0 = bd[0], s1 = bd[1];
#pragma unroll 4
  for (int c = 0; c < C_; ++c) {
    float f = dec_f(pooled[b * C_ + c]);
    s0 += f * Wd[c * 2 + 0];
    s1 += f * Wd[c * 2 + 1];
  }
  out[b * 2 + 0] = 1.f / (1.f + __expf(-s0));
  out[b * 2 + 1] = 1.f / (1.f + __expf(-s1));
}

// ---------------------------------------------------------------------------
extern "C" void kernel_launch(void* const* d_in, const int* in_sizes, int n_in,
                              void* d_out, int out_size, void* d_ws, size_t ws_size,
                              hipStream_t stream) {
  const int* idxC = (const int*)d_in[0];
  const int* idxL = (const int*)d_in[1];
  const int* idxR = (const int*)d_in[2];
  const float* emb = (const float*)d_in[3];
  const float* Wf = (const float*)d_in[4];
  const float* Uf = (const float*)d_in[5];
  const float* bf_ = (const float*)d_in[6];
  const float* Wb = (const float*)d_in[7];
  const float* Ub = (const float*)d_in[8];
  const float* bb_ = (const float*)d_in[9];
  const float* Wc = (const float*)d_in[10];
  const float* bc = (const float*)d_in[11];
  const float* Wd = (const float*)d_in[12];
  const float* bd = (const float*)d_in[13];

  char* ws = (char*)d_ws;
  unsigned short* x = (unsigned short*)ws;                          // 167,772,160 B
  unsigned int* pooled = (unsigned int*)(ws + 167772160);           // 131,072 B
  unsigned short* WfT = (unsigned short*)(ws + 167772160 + 131072); // 65,536 B
  unsigned short* WbT = WfT + 256 * 128;
  unsigned short* WcT = WbT + 256 * 128;
  unsigned short* UfT = WcT + 128 * 640;
  unsigned short* UbT = UfT + 256 * 256;

  hipMemsetAsync(pooled, 0, B_ * C_ * sizeof(unsigned int), stream);
  prep_kernel<<<64, 256, 0, stream>>>(Wf, Wb, Wc, Uf, Ub, WfT, WbT, WcT, UfT, UbT);
  embxw_kernel<<<dim3(128, 16, 2), 256, 0, stream>>>(idxL, idxR, emb, WfT, WbT,
                                                     bf_, bb_, x);
  pcur_kernel<<<dim3(128, 16), 256, 0, stream>>>(idxC, emb, WcT, bc, x);
  rnn_kernel<<<32, 256, 0, stream>>>(x, UfT, UbT, WcT);
  pool_kernel<<<256, 256, 0, stream>>>(x, pooled);
  dense_kernel<<<1, 256, 0, stream>>>(pooled, Wd, bd, (float*)d_out);
}

// Round 3
// 1004.535 us; speedup vs baseline: 1.0835x; 1.0259x over previous
//
#include <hip/hip_runtime.h>
#include <hip/hip_bf16.h>

// RCNN: bidirectional simple-RNN + conv1x1 + global max pool + dense sigmoid
// B=256 T=512 V=50000 E=128 H=256 C=128
//
// "unit" = 512 B = 64 lanes x 8 B (4 bf16). For batch-tile b0, time t, unit u
// lives in x-row (b0+u)*T+t. Short s = 64*q + 4*l15 + i  <->  (col 16u+4q+i,
// batch b0+l15).  x row layout (640 shorts): [0,256) h_f/xw_f units u=0..15,
// [256,384) e_cur units u=0..7 (q-halves split: col 16u+4qc+i -> row
// b0+u+8*(qc>>1), short 256+64*(qc&1)+4*l15), [384,640) h_b/xw_b units.
//
// rnn: 16 blocks x 8 waves; waves 0-3 run the fwd chain, 4-7 the bwd chain of
// the same batch tile -> 2 waves/SIMD so the two chains' latencies overlap.
// h overwrites xw in place (slot t); barrier drains LDS only (lgkmcnt).

#define B_ 256
#define T_ 512
#define E_ 128
#define H_ 256
#define C_ 128

typedef __attribute__((ext_vector_type(8))) short short8;
typedef __attribute__((ext_vector_type(4))) float float4v;
typedef __attribute__((ext_vector_type(2))) unsigned int uint2v;

__device__ inline unsigned short f2bf(float f) {
  unsigned u = __float_as_uint(f);
  u += 0x7fffu + ((u >> 16) & 1u);  // RNE
  return (unsigned short)(u >> 16);
}
__device__ inline unsigned pkbf(float a, float b) {
  __hip_bfloat162 h2 = __float22bfloat162_rn(float2{a, b});
  union { __hip_bfloat162 h; unsigned u; } cv;
  cv.h = h2;
  return cv.u;
}
__device__ inline float lo16f(unsigned u) { return __uint_as_float(u << 16); }
__device__ inline float hi16f(unsigned u) { return __uint_as_float(u & 0xffff0000u); }
__device__ inline float fast_tanh(float x) {
  float e = __expf(2.f * x);                 // inf ok -> 1
  float r = __builtin_amdgcn_rcpf(e + 1.f);
  return __builtin_fmaf(-2.f, r, 1.f);
}
__device__ inline unsigned enc_f(float f) {
  unsigned u = __float_as_uint(f);
  return (u & 0x80000000u) ? ~u : (u | 0x80000000u);
}
__device__ inline float dec_f(unsigned key) {
  unsigned bits = (key & 0x80000000u) ? (key ^ 0x80000000u) : ~key;
  return __uint_as_float(bits);
}
__device__ inline void sync_lds() {
  asm volatile("s_waitcnt lgkmcnt(0)\n\ts_barrier" ::: "memory");
}

// ---------------------------------------------------------------------------
// prep: transpose + bf16-cast weights. WfT/WbT:[256][128] WcT:[128][640]
// UfT/UbT:[256][256]  (all [n][k])
// ---------------------------------------------------------------------------
__global__ __launch_bounds__(256) void prep_kernel(
    const float* __restrict__ Wf, const float* __restrict__ Wb,
    const float* __restrict__ Wc, const float* __restrict__ Uf,
    const float* __restrict__ Ub,
    unsigned short* __restrict__ WfT, unsigned short* __restrict__ WbT,
    unsigned short* __restrict__ WcT, unsigned short* __restrict__ UfT,
    unsigned short* __restrict__ UbT) {
  int gid = blockIdx.x * 256 + threadIdx.x;
  int stride = gridDim.x * 256;
  for (int i = gid; i < 256 * 128; i += stride) {
    int n = i >> 7, k = i & 127;
    WfT[i] = f2bf(Wf[k * 256 + n]);
    WbT[i] = f2bf(Wb[k * 256 + n]);
  }
  for (int i = gid; i < 128 * 640; i += stride) {
    int n = i / 640, k = i - n * 640;
    WcT[i] = f2bf(Wc[k * 128 + n]);
  }
  for (int i = gid; i < 256 * 256; i += stride) {
    int n = i >> 8, k = i & 255;
    UfT[i] = f2bf(Uf[k * 256 + n]);
    UbT[i] = f2bf(Ub[k * 256 + n]);
  }
}

// ---------------------------------------------------------------------------
// embxw: xw^T = W^T . e^T + b, packed units into x (cols 0-255 / 384-639).
// grid (128 tquads, 16 btiles, 2 dirs), 256 thr (4 waves, 64 out-cols each).
// ---------------------------------------------------------------------------
__global__ __launch_bounds__(256) void embxw_kernel(
    const int* __restrict__ idxL, const int* __restrict__ idxR,
    const float* __restrict__ emb,
    const unsigned short* __restrict__ WfT, const unsigned short* __restrict__ WbT,
    const float* __restrict__ bfv, const float* __restrict__ bbv,
    unsigned short* __restrict__ x) {
  const int dir = blockIdx.z;
  const int* __restrict__ idx = dir ? idxR : idxL;
  const unsigned short* __restrict__ WT = dir ? WbT : WfT;
  const float* __restrict__ bias = dir ? bbv : bfv;
  const int t0 = blockIdx.x * 4;
  const int b0 = blockIdx.y * 16;
  const int tid = threadIdx.x;
  const int w = tid >> 6, lane = tid & 63, q = lane >> 4, l15 = lane & 15;

  short8 wfr[4][4];
#pragma unroll
  for (int mt = 0; mt < 4; ++mt)
#pragma unroll
    for (int kt = 0; kt < 4; ++kt)
      wfr[mt][kt] = *(const short8*)(WT + (64 * w + 16 * mt + l15) * 128 +
                                     kt * 32 + q * 8);
  float4v bv[4];
#pragma unroll
  for (int mt = 0; mt < 4; ++mt)
    bv[mt] = *(const float4v*)(bias + 64 * w + 16 * mt + 4 * q);

#pragma unroll 1
  for (int j = 0; j < 4; ++j) {
    const int t = t0 + j;
    const int er = idx[(b0 + l15) * T_ + t];
    const float* ep = emb + (size_t)er * E_;
    short8 efr[4];
#pragma unroll
    for (int kt = 0; kt < 4; ++kt) {
      const float* p8 = ep + kt * 32 + q * 8;
      float4v a0 = *(const float4v*)p8;
      float4v a1 = *(const float4v*)(p8 + 4);
      union { unsigned u[4]; short8 s; } cv;
      cv.u[0] = pkbf(a0[0], a0[1]);
      cv.u[1] = pkbf(a0[2], a0[3]);
      cv.u[2] = pkbf(a1[0], a1[1]);
      cv.u[3] = pkbf(a1[2], a1[3]);
      efr[kt] = cv.s;
    }
    float4v acc[4];
#pragma unroll
    for (int mt = 0; mt < 4; ++mt) acc[mt] = (float4v){0.f, 0.f, 0.f, 0.f};
#pragma unroll
    for (int kt = 0; kt < 4; ++kt)
#pragma unroll
      for (int mt = 0; mt < 4; ++mt)
        acc[mt] = __builtin_amdgcn_mfma_f32_16x16x32_bf16(wfr[mt][kt], efr[kt],
                                                          acc[mt], 0, 0, 0);
#pragma unroll
    for (int mt = 0; mt < 4; ++mt) {
      float4v v = acc[mt] + bv[mt];
      uint2v pk = {pkbf(v[0], v[1]), pkbf(v[2], v[3])};
      *(uint2v*)(x + ((size_t)(b0 + 4 * w + mt) * T_ + t) * 640 + dir * 384 +
                 lane * 4) = pk;
    }
  }
}

// ---------------------------------------------------------------------------
// ecur: gather e_cur -> bf16 units (q-half split layout) into x [256,384).
// grid (128 tquads, 16 btiles), 256 thr (4 waves, 1 t each).
// ---------------------------------------------------------------------------
__global__ __launch_bounds__(256) void ecur_kernel(
    const int* __restrict__ idxC, const float* __restrict__ emb,
    unsigned short* __restrict__ x) {
  const int b0 = blockIdx.y * 16;
  const int t = blockIdx.x * 4 + (threadIdx.x >> 6);
  const int lane = threadIdx.x & 63, q = lane >> 4, l15 = lane & 15;
  const int er = idxC[(b0 + l15) * T_ + t];
  const float* ep = emb + (size_t)er * E_;
#pragma unroll
  for (int u = 0; u < 8; ++u) {
    float4v a = *(const float4v*)(ep + 16 * u + 4 * q);
    uint2v pk = {pkbf(a[0], a[1]), pkbf(a[2], a[3])};
    int row = b0 + u + 8 * (q >> 1);
    *(uint2v*)(x + ((size_t)row * T_ + t) * 640 + 256 + 64 * (q & 1) +
               4 * l15) = pk;
  }
}

// ---------------------------------------------------------------------------
// rnn: h_t = tanh(xw_t + U^T h^T), dual-chain (fwd+bwd) per block.
// 16 blocks x 512 thr. h in-place over xw at slot t. U frags in registers.
// ---------------------------------------------------------------------------
__global__ __launch_bounds__(512, 2) void rnn_kernel(
    unsigned short* x, const unsigned short* __restrict__ UfT,
    const unsigned short* __restrict__ UbT) {
  const int b0 = blockIdx.x * 16;
  const int tid = threadIdx.x;
  const int wave = tid >> 6, lane = tid & 63, q = lane >> 4, l15 = lane & 15;
  const int chain = wave >> 2;  // 0 = fwd, 1 = bwd (one of each per SIMD)
  const int wv = wave & 3;      // wave within chain: 64 h-cols each
  const unsigned short* __restrict__ UT = chain ? UbT : UfT;
  const int xoff = chain ? 384 : 0;
  const int tstep = chain ? -1 : 1;
  const int t0 = chain ? (T_ - 1) : 0;
  const int dstep = tstep * 640;

  __shared__ __attribute__((aligned(16))) unsigned short hbuf[2][2][16][264];
  unsigned short* hb = &hbuf[chain][0][0][0];

  for (int i = tid; i < 4224; i += 512) {
    hbuf[0][0][0][i] = 0;
    hbuf[1][0][0][i] = 0;
  }

  // U^T A-fragments for this wave's 64 output cols
  short8 ufr[4][8];
#pragma unroll
  for (int mt = 0; mt < 4; ++mt)
#pragma unroll
    for (int kt = 0; kt < 8; ++kt)
      ufr[mt][kt] = *(const short8*)(UT + (64 * wv + 16 * mt + l15) * H_ +
                                     kt * 32 + q * 8);

  // per-lane running unit pointers (units u = 4*wv + mt)
  unsigned short* xq[4];
  uint2v cur[4];
#pragma unroll
  for (int mt = 0; mt < 4; ++mt) {
    unsigned short* base =
        x + (size_t)(b0 + 4 * wv + mt) * T_ * 640 + xoff + lane * 4;
    cur[mt] = *(const uint2v*)(base + (size_t)t0 * 640);
    xq[mt] = base + (size_t)(t0 + tstep) * 640;
  }

  __syncthreads();

  unsigned rd = 0;  // read-buffer offset in shorts (write = rd ^ 4224)

#pragma unroll 1
  for (int s = 0; s < T_; ++s) {
    // prefetch next xw (long latency, independent)
    uint2v nxt[4];
    if (s < T_ - 1) {
#pragma unroll
      for (int mt = 0; mt < 4; ++mt) nxt[mt] = *(const uint2v*)xq[mt];
    } else {
#pragma unroll
      for (int mt = 0; mt < 4; ++mt) nxt[mt] = cur[mt];
    }
#pragma unroll
    for (int mt = 0; mt < 4; ++mt) xq[mt] += dstep;

    // B-fragments of h(s-1) for this chain
    short8 afr[8];
#pragma unroll
    for (int kt = 0; kt < 8; ++kt)
      afr[kt] = *(const short8*)(hb + rd + l15 * 264 + kt * 32 + q * 8);

    // h-GEMM: D[m = out-col][n = batch]
    float4v acc[4];
#pragma unroll
    for (int mt = 0; mt < 4; ++mt) acc[mt] = (float4v){0.f, 0.f, 0.f, 0.f};
#pragma unroll
    for (int kt = 0; kt < 8; ++kt)
#pragma unroll
      for (int mt = 0; mt < 4; ++mt)
        acc[mt] = __builtin_amdgcn_mfma_f32_16x16x32_bf16(ufr[mt][kt], afr[kt],
                                                          acc[mt], 0, 0, 0);
    // epilogue: h = tanh(acc + xw); write LDS (b64) + global (in place, t_s)
#pragma unroll
    for (int mt = 0; mt < 4; ++mt) {
      float p0 = acc[mt][0] + lo16f(cur[mt].x);
      float p1 = acc[mt][1] + hi16f(cur[mt].x);
      float p2 = acc[mt][2] + lo16f(cur[mt].y);
      float p3 = acc[mt][3] + hi16f(cur[mt].y);
      uint2v hv = {pkbf(fast_tanh(p0), fast_tanh(p1)),
                   pkbf(fast_tanh(p2), fast_tanh(p3))};
      *(uint2v*)(hb + (rd ^ 4224) + l15 * 264 + 64 * wv + 16 * mt + 4 * q) = hv;
      *(uint2v*)(xq[mt] - 2 * dstep) = hv;  // slot t_s
    }
#pragma unroll
    for (int mt = 0; mt < 4; ++mt) cur[mt] = nxt[mt];
    rd ^= 4224;
    sync_lds();
  }
}

// ---------------------------------------------------------------------------
// convpool: out = max_t tanh(x_row @ Wc + bc). grid (16 btiles x 32 tchunks),
// 256 thr (4 waves x 32 c-cols). x tile staged through LDS per t (dbuf).
// ---------------------------------------------------------------------------
__global__ __launch_bounds__(256, 2) void convpool_kernel(
    const unsigned short* __restrict__ x, const unsigned short* __restrict__ WcT,
    const float* __restrict__ bc, unsigned int* __restrict__ pooled) {
  const int b0 = (blockIdx.x & 15) * 16;
  const int t0 = (blockIdx.x >> 4) * 16;
  const int tid = threadIdx.x;
  const int w = tid >> 6, lane = tid & 63, q = lane >> 4, l15 = lane & 15;

  __shared__ __attribute__((aligned(16))) unsigned short tile[2][16][648];

  // Wc^T A-fragments: 2 col-tiles x 20 k-tiles
  short8 wfr[2][20];
#pragma unroll
  for (int ct = 0; ct < 2; ++ct)
#pragma unroll
    for (int kt = 0; kt < 20; ++kt)
      wfr[ct][kt] = *(const short8*)(WcT +
                                     (size_t)(32 * w + 16 * ct + l15) * 640 +
                                     kt * 32 + q * 8);
  float4v bv[2];
#pragma unroll
  for (int ct = 0; ct < 2; ++ct)
    bv[ct] = *(const float4v*)(bc + 32 * w + 16 * ct + 4 * q);

  float4v mx[2];
  mx[0] = (float4v){-1e30f, -1e30f, -1e30f, -1e30f};
  mx[1] = mx[0];

  const int srow = tid >> 4, ssub = tid & 15;  // staging: 16 thr per row
  // stage t0 into buf 0
  {
    const unsigned short* src = x + ((size_t)(b0 + srow) * T_ + t0) * 640;
#pragma unroll
    for (int j = 0; j < 5; ++j)
      *(short8*)&tile[0][srow][ssub * 8 + j * 128] =
          *(const short8*)(src + ssub * 8 + j * 128);
  }
  __syncthreads();

#pragma unroll 1
  for (int j = 0; j < 16; ++j) {
    const int t = t0 + j;
    const int buf = j & 1;
    if (j < 15) {  // stage next t into other buffer
      const unsigned short* src = x + ((size_t)(b0 + srow) * T_ + t + 1) * 640;
#pragma unroll
      for (int jj = 0; jj < 5; ++jj)
        *(short8*)&tile[buf ^ 1][srow][ssub * 8 + jj * 128] =
            *(const short8*)(src + ssub * 8 + jj * 128);
    }
    float4v acc[2];
    acc[0] = (float4v){0.f, 0.f, 0.f, 0.f};
    acc[1] = (float4v){0.f, 0.f, 0.f, 0.f};
#pragma unroll
    for (int kt = 0; kt < 20; ++kt) {
      int row, so1, so2;
      if (kt < 8) {            // h_f region, cols k = 32kt + 8q
        row = 2 * kt + (q >> 1);
        so1 = 64 * (2 * (q & 1)) + 4 * l15;
        so2 = so1 + 64;
      } else if (kt < 12) {    // e_cur region (q-half split rows)
        row = 2 * (kt - 8) + (q >> 1) + 8 * (q & 1);
        so1 = 256 + 4 * l15;
        so2 = 320 + 4 * l15;
      } else {                 // h_b region
        row = 2 * (kt - 12) + (q >> 1);
        so1 = 384 + 64 * (2 * (q & 1)) + 4 * l15;
        so2 = so1 + 64;
      }
      union { unsigned u[4]; short8 s; } cv;
      uint2v c1 = *(const uint2v*)&tile[buf][row][so1];
      uint2v c2 = *(const uint2v*)&tile[buf][row][so2];
      cv.u[0] = c1.x; cv.u[1] = c1.y; cv.u[2] = c2.x; cv.u[3] = c2.y;
      acc[0] = __builtin_amdgcn_mfma_f32_16x16x32_bf16(wfr[0][kt], cv.s,
                                                       acc[0], 0, 0, 0);
      acc[1] = __builtin_amdgcn_mfma_f32_16x16x32_bf16(wfr[1][kt], cv.s,
                                                       acc[1], 0, 0, 0);
    }
#pragma unroll
    for (int ct = 0; ct < 2; ++ct)
#pragma unroll
      for (int i = 0; i < 4; ++i)
        mx[ct][i] = fmaxf(mx[ct][i], fast_tanh(acc[ct][i] + bv[ct][i]));
    __syncthreads();
  }
#pragma unroll
  for (int ct = 0; ct < 2; ++ct)
#pragma unroll
    for (int i = 0; i < 4; ++i)
      atomicMax(pooled + (b0 + l15) * C_ + 32 * w + 16 * ct + 4 * q + i,
                enc_f(mx[ct][i]));
}

// ---------------------------------------------------------------------------
// dense: out = sigmoid(pooled @ Wd + bd)  [256,128]@[128,2]
// ---------------------------------------------------------------------------
__global__ __launch_bounds__(256) void dense_kernel(
    const unsigned int* __restrict__ pooled, const float* __restrict__ Wd,
    const float* __restrict__ bd, float* __restrict__ out) {
  int b = threadIdx.x;
  float s0 = bd[0], s1 = bd[1];
#pragma unroll 4
  for (int c = 0; c < C_; ++c) {
    float f = dec_f(pooled[b * C_ + c]);
    s0 += f * Wd[c * 2 + 0];
    s1 += f * Wd[c * 2 + 1];
  }
  out[b * 2 + 0] = 1.f / (1.f + __expf(-s0));
  out[b * 2 + 1] = 1.f / (1.f + __expf(-s1));
}

// ---------------------------------------------------------------------------
extern "C" void kernel_launch(void* const* d_in, const int* in_sizes, int n_in,
                              void* d_out, int out_size, void* d_ws, size_t ws_size,
                              hipStream_t stream) {
  const int* idxC = (const int*)d_in[0];
  const int* idxL = (const int*)d_in[1];
  const int* idxR = (const int*)d_in[2];
  const float* emb = (const float*)d_in[3];
  const float* Wf = (const float*)d_in[4];
  const float* Uf = (const float*)d_in[5];
  const float* bf_ = (const float*)d_in[6];
  const float* Wb = (const float*)d_in[7];
  const float* Ub = (const float*)d_in[8];
  const float* bb_ = (const float*)d_in[9];
  const float* Wc = (const float*)d_in[10];
  const float* bc = (const float*)d_in[11];
  const float* Wd = (const float*)d_in[12];
  const float* bd = (const float*)d_in[13];

  char* ws = (char*)d_ws;
  unsigned short* x = (unsigned short*)ws;                          // 167,772,160 B
  unsigned int* pooled = (unsigned int*)(ws + 167772160);           // 131,072 B
  unsigned short* WfT = (unsigned short*)(ws + 167772160 + 131072);
  unsigned short* WbT = WfT + 256 * 128;
  unsigned short* WcT = WbT + 256 * 128;
  unsigned short* UfT = WcT + 128 * 640;
  unsigned short* UbT = UfT + 256 * 256;

  hipMemsetAsync(pooled, 0, B_ * C_ * sizeof(unsigned int), stream);
  prep_kernel<<<64, 256, 0, stream>>>(Wf, Wb, Wc, Uf, Ub, WfT, WbT, WcT, UfT, UbT);
  embxw_kernel<<<dim3(128, 16, 2), 256, 0, stream>>>(idxL, idxR, emb, WfT, WbT,
                                                     bf_, bb_, x);
  ecur_kernel<<<dim3(128, 16), 256, 0, stream>>>(idxC, emb, x);
  rnn_kernel<<<16, 512, 0, stream>>>(x, UfT, UbT);
  convpool_kernel<<<512, 256, 0, stream>>>(x, WcT, bc, pooled);
  dense_kernel<<<1, 256, 0, stream>>>(pooled, Wd, bd, (float*)d_out);
}

// Round 4
// 634.565 us; speedup vs baseline: 1.7153x; 1.5830x over previous
//
#include <hip/hip_runtime.h>
#include <hip/hip_bf16.h>

// RCNN: bidirectional simple-RNN + conv1x1 + global max pool + dense sigmoid
// B=256 T=512 V=50000 E=128 H=256 C=128
//
// "unit" = 512 B = 64 lanes x 8 B (4 bf16). For batch-tile b0, time t, unit u
// lives in x-row (b0+u)*T+t. Short s = 64*q + 4*l15 + i  <->  (col 16u+4q+i,
// batch b0+l15).  x row layout (640 shorts): [0,256) h_f/xw_f units u=0..15,
// [256,384) e_cur units u=0..7 (q-half split), [384,640) h_b/xw_b units.
//
// rnn: 32 blocks (16 btiles x 2 dirs) x 8 waves x 32 cols each -> 32 CUs,
// 2 waves/SIMD. MFMA C-operand seeded with xw (no epilogue add / acc init).
// T-loop unrolled x2, xw prefetch distance 4, h in-place over xw slot t.
// Barrier drains LDS only (lgkmcnt) - global ops pipeline across steps.

#define B_ 256
#define T_ 512
#define E_ 128
#define H_ 256
#define C_ 128

typedef __attribute__((ext_vector_type(8))) short short8;
typedef __attribute__((ext_vector_type(4))) float float4v;
typedef __attribute__((ext_vector_type(2))) unsigned int uint2v;

__device__ inline unsigned short f2bf(float f) {
  unsigned u = __float_as_uint(f);
  u += 0x7fffu + ((u >> 16) & 1u);  // RNE
  return (unsigned short)(u >> 16);
}
__device__ inline unsigned pkbf(float a, float b) {
  __hip_bfloat162 h2 = __float22bfloat162_rn(float2{a, b});
  union { __hip_bfloat162 h; unsigned u; } cv;
  cv.h = h2;
  return cv.u;
}
__device__ inline float lo16f(unsigned u) { return __uint_as_float(u << 16); }
__device__ inline float hi16f(unsigned u) { return __uint_as_float(u & 0xffff0000u); }
__device__ inline float fast_tanh(float x) {
  float e = __expf(2.f * x);                 // inf ok -> 1
  float r = __builtin_amdgcn_rcpf(e + 1.f);
  return __builtin_fmaf(-2.f, r, 1.f);
}
__device__ inline unsigned enc_f(float f) {
  unsigned u = __float_as_uint(f);
  return (u & 0x80000000u) ? ~u : (u | 0x80000000u);
}
__device__ inline float dec_f(unsigned key) {
  unsigned bits = (key & 0x80000000u) ? (key ^ 0x80000000u) : ~key;
  return __uint_as_float(bits);
}
__device__ inline void sync_lds() {
  asm volatile("s_waitcnt lgkmcnt(0)\n\ts_barrier" ::: "memory");
}

// ---------------------------------------------------------------------------
// prep: transpose + bf16-cast weights. WfT/WbT:[256][128] WcT:[128][640]
// UfT/UbT:[256][256]  (all [n][k])
// ---------------------------------------------------------------------------
__global__ __launch_bounds__(256) void prep_kernel(
    const float* __restrict__ Wf, const float* __restrict__ Wb,
    const float* __restrict__ Wc, const float* __restrict__ Uf,
    const float* __restrict__ Ub,
    unsigned short* __restrict__ WfT, unsigned short* __restrict__ WbT,
    unsigned short* __restrict__ WcT, unsigned short* __restrict__ UfT,
    unsigned short* __restrict__ UbT) {
  int gid = blockIdx.x * 256 + threadIdx.x;
  int stride = gridDim.x * 256;
  for (int i = gid; i < 256 * 128; i += stride) {
    int n = i >> 7, k = i & 127;
    WfT[i] = f2bf(Wf[k * 256 + n]);
    WbT[i] = f2bf(Wb[k * 256 + n]);
  }
  for (int i = gid; i < 128 * 640; i += stride) {
    int n = i / 640, k = i - n * 640;
    WcT[i] = f2bf(Wc[k * 128 + n]);
  }
  for (int i = gid; i < 256 * 256; i += stride) {
    int n = i >> 8, k = i & 255;
    UfT[i] = f2bf(Uf[k * 256 + n]);
    UbT[i] = f2bf(Ub[k * 256 + n]);
  }
}

// ---------------------------------------------------------------------------
// embxw: xw^T = W^T . e^T + b, packed units into x (cols 0-255 / 384-639).
// grid (128 tquads, 16 btiles, 2 dirs), 256 thr (4 waves, 64 out-cols each).
// ---------------------------------------------------------------------------
__global__ __launch_bounds__(256) void embxw_kernel(
    const int* __restrict__ idxL, const int* __restrict__ idxR,
    const float* __restrict__ emb,
    const unsigned short* __restrict__ WfT, const unsigned short* __restrict__ WbT,
    const float* __restrict__ bfv, const float* __restrict__ bbv,
    unsigned short* __restrict__ x) {
  const int dir = blockIdx.z;
  const int* __restrict__ idx = dir ? idxR : idxL;
  const unsigned short* __restrict__ WT = dir ? WbT : WfT;
  const float* __restrict__ bias = dir ? bbv : bfv;
  const int t0 = blockIdx.x * 4;
  const int b0 = blockIdx.y * 16;
  const int tid = threadIdx.x;
  const int w = tid >> 6, lane = tid & 63, q = lane >> 4, l15 = lane & 15;

  short8 wfr[4][4];
#pragma unroll
  for (int mt = 0; mt < 4; ++mt)
#pragma unroll
    for (int kt = 0; kt < 4; ++kt)
      wfr[mt][kt] = *(const short8*)(WT + (64 * w + 16 * mt + l15) * 128 +
                                     kt * 32 + q * 8);
  float4v bv[4];
#pragma unroll
  for (int mt = 0; mt < 4; ++mt)
    bv[mt] = *(const float4v*)(bias + 64 * w + 16 * mt + 4 * q);

#pragma unroll 1
  for (int j = 0; j < 4; ++j) {
    const int t = t0 + j;
    const int er = idx[(b0 + l15) * T_ + t];
    const float* ep = emb + (size_t)er * E_;
    short8 efr[4];
#pragma unroll
    for (int kt = 0; kt < 4; ++kt) {
      const float* p8 = ep + kt * 32 + q * 8;
      float4v a0 = *(const float4v*)p8;
      float4v a1 = *(const float4v*)(p8 + 4);
      union { unsigned u[4]; short8 s; } cv;
      cv.u[0] = pkbf(a0[0], a0[1]);
      cv.u[1] = pkbf(a0[2], a0[3]);
      cv.u[2] = pkbf(a1[0], a1[1]);
      cv.u[3] = pkbf(a1[2], a1[3]);
      efr[kt] = cv.s;
    }
    float4v acc[4];
#pragma unroll
    for (int mt = 0; mt < 4; ++mt) acc[mt] = (float4v){0.f, 0.f, 0.f, 0.f};
#pragma unroll
    for (int kt = 0; kt < 4; ++kt)
#pragma unroll
      for (int mt = 0; mt < 4; ++mt)
        acc[mt] = __builtin_amdgcn_mfma_f32_16x16x32_bf16(wfr[mt][kt], efr[kt],
                                                          acc[mt], 0, 0, 0);
#pragma unroll
    for (int mt = 0; mt < 4; ++mt) {
      float4v v = acc[mt] + bv[mt];
      uint2v pk = {pkbf(v[0], v[1]), pkbf(v[2], v[3])};
      *(uint2v*)(x + ((size_t)(b0 + 4 * w + mt) * T_ + t) * 640 + dir * 384 +
                 lane * 4) = pk;
    }
  }
}

// ---------------------------------------------------------------------------
// ecur: gather e_cur -> bf16 units (q-half split layout) into x [256,384).
// grid (128 tquads, 16 btiles), 256 thr (4 waves, 1 t each).
// ---------------------------------------------------------------------------
__global__ __launch_bounds__(256) void ecur_kernel(
    const int* __restrict__ idxC, const float* __restrict__ emb,
    unsigned short* __restrict__ x) {
  const int b0 = blockIdx.y * 16;
  const int t = blockIdx.x * 4 + (threadIdx.x >> 6);
  const int lane = threadIdx.x & 63, q = lane >> 4, l15 = lane & 15;
  const int er = idxC[(b0 + l15) * T_ + t];
  const float* ep = emb + (size_t)er * E_;
#pragma unroll
  for (int u = 0; u < 8; ++u) {
    float4v a = *(const float4v*)(ep + 16 * u + 4 * q);
    uint2v pk = {pkbf(a[0], a[1]), pkbf(a[2], a[3])};
    int row = b0 + u + 8 * (q >> 1);
    *(uint2v*)(x + ((size_t)row * T_ + t) * 640 + 256 + 64 * (q & 1) +
               4 * l15) = pk;
  }
}

// ---------------------------------------------------------------------------
// rnn: h_t = tanh(U^T h^T ; C-seed = xw_t). One chain per block, 8 waves x
// 32 cols. 32 blocks. T-loop unrolled x2; xw prefetch distance 4.
// ---------------------------------------------------------------------------
__global__ __launch_bounds__(512, 2) void rnn_kernel(
    unsigned short* x, const unsigned short* __restrict__ UfT,
    const unsigned short* __restrict__ UbT) {
  const int dir = blockIdx.x & 1;
  const int b0 = (blockIdx.x >> 1) * 16;
  const unsigned short* __restrict__ UT = dir ? UbT : UfT;
  const int xoff = dir ? 384 : 0;
  const int tstep = dir ? -1 : 1;
  const int t0 = dir ? (T_ - 1) : 0;
  const ptrdiff_t dstep = (ptrdiff_t)tstep * 640;  // shorts per t-step

  const int tid = threadIdx.x;
  const int wv = tid >> 6, lane = tid & 63, q = lane >> 4, l15 = lane & 15;

  // stride 280 shorts = 140 dw = 12 mod 32 -> b128 bank-start 4*(3*l15+q)%32,
  // exactly 2 lanes per start (2-way = free)
  __shared__ __attribute__((aligned(16))) unsigned short hbuf[2][16][280];
  unsigned short* hb0 = &hbuf[0][0][0];
  unsigned short* hb1 = &hbuf[1][0][0];

  for (int i = tid; i < 16 * 280; i += 512) hb0[i] = 0;

  // U^T A-fragments for this wave's 32 output cols
  short8 ufr[2][8];
#pragma unroll
  for (int mt = 0; mt < 2; ++mt)
#pragma unroll
    for (int kt = 0; kt < 8; ++kt)
      ufr[mt][kt] = *(const short8*)(UT + (32 * wv + 16 * mt + l15) * H_ +
                                     kt * 32 + q * 8);

  // per-lane unit pointers: units u = 2*wv + mt
  unsigned short* ptrS[2];        // store slot (step t of current pair)
  const unsigned short* ptrL[2];  // load slot (t + 4*tstep)
  uint2v curA[2], curB[2], infA[2], infB[2];
#pragma unroll
  for (int mt = 0; mt < 2; ++mt) {
    unsigned short* base =
        x + (size_t)(b0 + 2 * wv + mt) * T_ * 640 + xoff + lane * 4;
    unsigned short* bt = base + (ptrdiff_t)t0 * 640;
    curA[mt] = *(const uint2v*)(bt);
    curB[mt] = *(const uint2v*)(bt + dstep);
    infA[mt] = *(const uint2v*)(bt + 2 * dstep);
    infB[mt] = *(const uint2v*)(bt + 3 * dstep);
    ptrS[mt] = bt;
    ptrL[mt] = bt + 4 * dstep;
  }

  const unsigned lrd = l15 * 280;  // LDS read row base (shorts)
  const unsigned lwr = l15 * 280 + 32 * wv;  // LDS write base (+16mt+4q)

  __syncthreads();

#pragma unroll 1
  for (int p = 0; p < 256; ++p) {
    // prefetch pair p+2's xw (steps 2p+4, 2p+5)
    uint2v ldA[2], ldB[2];
    if (p < 254) {
#pragma unroll
      for (int mt = 0; mt < 2; ++mt) {
        ldA[mt] = *(const uint2v*)(ptrL[mt]);
        ldB[mt] = *(const uint2v*)(ptrL[mt] + dstep);
      }
    } else {
#pragma unroll
      for (int mt = 0; mt < 2; ++mt) { ldA[mt] = infA[mt]; ldB[mt] = infB[mt]; }
    }
#pragma unroll
    for (int mt = 0; mt < 2; ++mt) ptrL[mt] += 2 * dstep;

    // ---- STEP A: read hb0, write hb1 ----
    {
      short8 afr[8];
#pragma unroll
      for (int kt = 0; kt < 8; ++kt)
        afr[kt] = *(const short8*)(hb0 + lrd + kt * 32 + q * 8);
      float4v acc[2];
#pragma unroll
      for (int mt = 0; mt < 2; ++mt)
        acc[mt] = (float4v){lo16f(curA[mt].x), hi16f(curA[mt].x),
                            lo16f(curA[mt].y), hi16f(curA[mt].y)};
#pragma unroll
      for (int kt = 0; kt < 8; ++kt)
#pragma unroll
        for (int mt = 0; mt < 2; ++mt)
          acc[mt] = __builtin_amdgcn_mfma_f32_16x16x32_bf16(
              ufr[mt][kt], afr[kt], acc[mt], 0, 0, 0);
#pragma unroll
      for (int mt = 0; mt < 2; ++mt) {
        uint2v hv = {pkbf(fast_tanh(acc[mt][0]), fast_tanh(acc[mt][1])),
                     pkbf(fast_tanh(acc[mt][2]), fast_tanh(acc[mt][3]))};
        *(uint2v*)(hb1 + lwr + 16 * mt + 4 * q) = hv;
        *(uint2v*)ptrS[mt] = hv;
      }
    }
    sync_lds();

    // ---- STEP B: read hb1, write hb0 ----
    {
      short8 afr[8];
#pragma unroll
      for (int kt = 0; kt < 8; ++kt)
        afr[kt] = *(const short8*)(hb1 + lrd + kt * 32 + q * 8);
      float4v acc[2];
#pragma unroll
      for (int mt = 0; mt < 2; ++mt)
        acc[mt] = (float4v){lo16f(curB[mt].x), hi16f(curB[mt].x),
                            lo16f(curB[mt].y), hi16f(curB[mt].y)};
#pragma unroll
      for (int kt = 0; kt < 8; ++kt)
#pragma unroll
        for (int mt = 0; mt < 2; ++mt)
          acc[mt] = __builtin_amdgcn_mfma_f32_16x16x32_bf16(
              ufr[mt][kt], afr[kt], acc[mt], 0, 0, 0);
#pragma unroll
      for (int mt = 0; mt < 2; ++mt) {
        uint2v hv = {pkbf(fast_tanh(acc[mt][0]), fast_tanh(acc[mt][1])),
                     pkbf(fast_tanh(acc[mt][2]), fast_tanh(acc[mt][3]))};
        *(uint2v*)(hb0 + lwr + 16 * mt + 4 * q) = hv;
        *(uint2v*)(ptrS[mt] + dstep) = hv;
      }
    }
#pragma unroll
    for (int mt = 0; mt < 2; ++mt) {
      ptrS[mt] += 2 * dstep;
      curA[mt] = infA[mt];
      curB[mt] = infB[mt];
      infA[mt] = ldA[mt];
      infB[mt] = ldB[mt];
    }
    sync_lds();
  }
}

// ---------------------------------------------------------------------------
// convpool: out = max_t tanh(x_row @ Wc + bc). grid (16 btiles x 32 tchunks),
// 256 thr (4 waves x 32 c-cols). x tile staged through LDS per t (dbuf).
// ---------------------------------------------------------------------------
__global__ __launch_bounds__(256, 2) void convpool_kernel(
    const unsigned short* __restrict__ x, const unsigned short* __restrict__ WcT,
    const float* __restrict__ bc, unsigned int* __restrict__ pooled) {
  const int b0 = (blockIdx.x & 15) * 16;
  const int t0 = (blockIdx.x >> 4) * 16;
  const int tid = threadIdx.x;
  const int w = tid >> 6, lane = tid & 63, q = lane >> 4, l15 = lane & 15;

  __shared__ __attribute__((aligned(16))) unsigned short tile[2][16][648];

  short8 wfr[2][20];
#pragma unroll
  for (int ct = 0; ct < 2; ++ct)
#pragma unroll
    for (int kt = 0; kt < 20; ++kt)
      wfr[ct][kt] = *(const short8*)(WcT +
                                     (size_t)(32 * w + 16 * ct + l15) * 640 +
                                     kt * 32 + q * 8);
  float4v bv[2];
#pragma unroll
  for (int ct = 0; ct < 2; ++ct)
    bv[ct] = *(const float4v*)(bc + 32 * w + 16 * ct + 4 * q);

  float4v mx[2];
  mx[0] = (float4v){-1e30f, -1e30f, -1e30f, -1e30f};
  mx[1] = mx[0];

  const int srow = tid >> 4, ssub = tid & 15;
  {
    const unsigned short* src = x + ((size_t)(b0 + srow) * T_ + t0) * 640;
#pragma unroll
    for (int j = 0; j < 5; ++j)
      *(short8*)&tile[0][srow][ssub * 8 + j * 128] =
          *(const short8*)(src + ssub * 8 + j * 128);
  }
  __syncthreads();

#pragma unroll 1
  for (int j = 0; j < 16; ++j) {
    const int t = t0 + j;
    const int buf = j & 1;
    if (j < 15) {
      const unsigned short* src = x + ((size_t)(b0 + srow) * T_ + t + 1) * 640;
#pragma unroll
      for (int jj = 0; jj < 5; ++jj)
        *(short8*)&tile[buf ^ 1][srow][ssub * 8 + jj * 128] =
            *(const short8*)(src + ssub * 8 + jj * 128);
    }
    float4v acc[2];
    acc[0] = (float4v){0.f, 0.f, 0.f, 0.f};
    acc[1] = (float4v){0.f, 0.f, 0.f, 0.f};
#pragma unroll
    for (int kt = 0; kt < 20; ++kt) {
      int row, so1, so2;
      if (kt < 8) {
        row = 2 * kt + (q >> 1);
        so1 = 64 * (2 * (q & 1)) + 4 * l15;
        so2 = so1 + 64;
      } else if (kt < 12) {
        row = 2 * (kt - 8) + (q >> 1) + 8 * (q & 1);
        so1 = 256 + 4 * l15;
        so2 = 320 + 4 * l15;
      } else {
        row = 2 * (kt - 12) + (q >> 1);
        so1 = 384 + 64 * (2 * (q & 1)) + 4 * l15;
        so2 = so1 + 64;
      }
      union { unsigned u[4]; short8 s; } cv;
      uint2v c1 = *(const uint2v*)&tile[buf][row][so1];
      uint2v c2 = *(const uint2v*)&tile[buf][row][so2];
      cv.u[0] = c1.x; cv.u[1] = c1.y; cv.u[2] = c2.x; cv.u[3] = c2.y;
      acc[0] = __builtin_amdgcn_mfma_f32_16x16x32_bf16(wfr[0][kt], cv.s,
                                                       acc[0], 0, 0, 0);
      acc[1] = __builtin_amdgcn_mfma_f32_16x16x32_bf16(wfr[1][kt], cv.s,
                                                       acc[1], 0, 0, 0);
    }
#pragma unroll
    for (int ct = 0; ct < 2; ++ct)
#pragma unroll
      for (int i = 0; i < 4; ++i)
        mx[ct][i] = fmaxf(mx[ct][i], fast_tanh(acc[ct][i] + bv[ct][i]));
    __syncthreads();
  }
#pragma unroll
  for (int ct = 0; ct < 2; ++ct)
#pragma unroll
    for (int i = 0; i < 4; ++i)
      atomicMax(pooled + (b0 + l15) * C_ + 32 * w + 16 * ct + 4 * q + i,
                enc_f(mx[ct][i]));
}

// ---------------------------------------------------------------------------
// dense: out = sigmoid(pooled @ Wd + bd)  [256,128]@[128,2]
// ---------------------------------------------------------------------------
__global__ __launch_bounds__(256) void dense_kernel(
    const unsigned int* __restrict__ pooled, const float* __restrict__ Wd,
    const float* __restrict__ bd, float* __restrict__ out) {
  int b = threadIdx.x;
  float s0 = bd[0], s1 = bd[1];
#pragma unroll 4
  for (int c = 0; c < C_; ++c) {
    float f = dec_f(pooled[b * C_ + c]);
    s0 += f * Wd[c * 2 + 0];
    s1 += f * Wd[c * 2 + 1];
  }
  out[b * 2 + 0] = 1.f / (1.f + __expf(-s0));
  out[b * 2 + 1] = 1.f / (1.f + __expf(-s1));
}

// ---------------------------------------------------------------------------
extern "C" void kernel_launch(void* const* d_in, const int* in_sizes, int n_in,
                              void* d_out, int out_size, void* d_ws, size_t ws_size,
                              hipStream_t stream) {
  const int* idxC = (const int*)d_in[0];
  const int* idxL = (const int*)d_in[1];
  const int* idxR = (const int*)d_in[2];
  const float* emb = (const float*)d_in[3];
  const float* Wf = (const float*)d_in[4];
  const float* Uf = (const float*)d_in[5];
  const float* bf_ = (const float*)d_in[6];
  const float* Wb = (const float*)d_in[7];
  const float* Ub = (const float*)d_in[8];
  const float* bb_ = (const float*)d_in[9];
  const float* Wc = (const float*)d_in[10];
  const float* bc = (const float*)d_in[11];
  const float* Wd = (const float*)d_in[12];
  const float* bd = (const float*)d_in[13];

  char* ws = (char*)d_ws;
  unsigned short* x = (unsigned short*)ws;                          // 167,772,160 B
  unsigned int* pooled = (unsigned int*)(ws + 167772160);           // 131,072 B
  unsigned short* WfT = (unsigned short*)(ws + 167772160 + 131072);
  unsigned short* WbT = WfT + 256 * 128;
  unsigned short* WcT = WbT + 256 * 128;
  unsigned short* UfT = WcT + 128 * 640;
  unsigned short* UbT = UfT + 256 * 256;

  hipMemsetAsync(pooled, 0, B_ * C_ * sizeof(unsigned int), stream);
  prep_kernel<<<64, 256, 0, stream>>>(Wf, Wb, Wc, Uf, Ub, WfT, WbT, WcT, UfT, UbT);
  embxw_kernel<<<dim3(128, 16, 2), 256, 0, stream>>>(idxL, idxR, emb, WfT, WbT,
                                                     bf_, bb_, x);
  ecur_kernel<<<dim3(128, 16), 256, 0, stream>>>(idxC, emb, x);
  rnn_kernel<<<32, 512, 0, stream>>>(x, UfT, UbT);
  convpool_kernel<<<512, 256, 0, stream>>>(x, WcT, bc, pooled);
  dense_kernel<<<1, 256, 0, stream>>>(pooled, Wd, bd, (float*)d_out);
}